// Round 6
// baseline (631.599 us; speedup 1.0000x reference)
//
#include <hip/hip_runtime.h>
#include <hip/hip_bf16.h>

// Problem constants (GATModule: N=8192, IN=128, OUT=64, H=4) — fp32 inputs/output.
#define NN   8192
#define IND  128
#define OUTD 64
#define NH   4
#define NEG_SLOPE 0.2f
#define BN_EPS 1e-5f

typedef __attribute__((ext_vector_type(8))) short bf16x8;   // MFMA A/B frag (8 bf16)
typedef __attribute__((ext_vector_type(4))) float f32x4;    // MFMA C/D frag
typedef __attribute__((ext_vector_type(4))) int   i32x4;

static __device__ __forceinline__ float bf2f(short s) {
    union { unsigned u; float f; } v; v.u = ((unsigned)(unsigned short)s) << 16; return v.f;
}
static __device__ __forceinline__ short f2bf(float f) {
    union { float f; unsigned u; } v; v.f = f;
    return (short)((v.u + 0x8000u) >> 16);
}

// ---------------- K0: repack W[h][k][o] fp32 -> WB bf16 [h][k/8][o][k%8] (B-frag) ----------
__global__ __launch_bounds__(256) void k0_repackW(const float* __restrict__ W,
                                                  short* __restrict__ WB) {
    int tid = blockIdx.x * 256 + threadIdx.x;      // 0..32767
    int o = tid & 63, i = (tid >> 6) & 127, h = tid >> 13;
    WB[((h * 16 + (i >> 3)) * 64 + o) * 8 + (i & 7)] = f2bf(W[(h * 128 + i) * 64 + o]);
}

// ---------------- K1: h = x@W per head (MFMA); store hB bf16 + exp tables ------------------
// grid 512 (16 rows each), block 256 (wave w = head w)
__global__ __launch_bounds__(256) void k1_feat(const float* __restrict__ x,
                                               const short* __restrict__ WB,
                                               const float* __restrict__ a_i,
                                               const float* __restrict__ a_j,
                                               short* __restrict__ hB,
                                               float* __restrict__ t_ei,  float* __restrict__ t_E1i,
                                               float* __restrict__ t_E2i, float* __restrict__ t_nj,
                                               float* __restrict__ t_E1j, float* __restrict__ t_E2j) {
    int w = threadIdx.x >> 6;        // head
    int l = threadIdx.x & 63;
    int quad = l >> 4, lx = l & 15;
    int rb = blockIdx.x;             // 16-row block

    f32x4 acc[4] = {};               // 4 o-tiles of 16
#pragma unroll
    for (int ks = 0; ks < 4; ++ks) { // K=128 in 4 steps of 32
        const float* xp = x + (rb * 16 + lx) * IND + ks * 32 + quad * 8;
        f32x4 xa = *(const f32x4*)xp;
        f32x4 xb = *(const f32x4*)(xp + 4);
        bf16x8 af;
#pragma unroll
        for (int j = 0; j < 4; ++j) { af[j] = f2bf(xa[j]); af[4 + j] = f2bf(xb[j]); }
#pragma unroll
        for (int ot = 0; ot < 4; ++ot) {
            bf16x8 bf = *(const bf16x8*)(WB + ((w * 16 + ks * 4 + quad) * 64 + ot * 16 + lx) * 8);
            acc[ot] = __builtin_amdgcn_mfma_f32_16x16x32_bf16(af, bf, acc[ot], 0, 0, 0);
        }
    }
    float aiv[4], ajv[4];
#pragma unroll
    for (int ot = 0; ot < 4; ++ot) {
        aiv[ot] = a_i[w * 64 + ot * 16 + lx];
        ajv[ot] = a_j[w * 64 + ot * 16 + lx];
    }
#pragma unroll
    for (int reg = 0; reg < 4; ++reg) {
        int row = rb * 16 + quad * 4 + reg;       // C-layout: row=quad*4+reg, col=lane&15
        float ei = 0.f, ej = 0.f;
#pragma unroll
        for (int ot = 0; ot < 4; ++ot) {
            float hv = acc[ot][reg];
            ei += hv * aiv[ot];
            ej += hv * ajv[ot];
        }
#pragma unroll
        for (int m = 1; m <= 8; m <<= 1) {        // reduce over the 16 lanes of this row
            ei += __shfl_xor(ei, m, 64);
            ej += __shfl_xor(ej, m, 64);
        }
        if (lx == reg) {
            t_ei [w * NN + row] = ei;
            t_E1i[w * NN + row] = expf(ei);
            t_E2i[w * NN + row] = expf(NEG_SLOPE * ei);
            t_nj [w * NN + row] = -ej;
            t_E1j[w * NN + row] = expf(ej);
            t_E2j[w * NN + row] = expf(NEG_SLOPE * ej);
        }
#pragma unroll
        for (int ot = 0; ot < 4; ++ot) {          // hB[h][n/8][o][n%8]
            int o = ot * 16 + lx;
            hB[((w * 1024 + (row >> 3)) * 64 + o) * 8 + (row & 7)] = f2bf(acc[ot][reg]);
        }
    }
}

// ---------------- K2: main attention kernel ------------------------------------------------
// grid 1024 = 128 rowblocks(64) x 8 K-splits(1024 cols); block 256 = 4 waves, wave w = head
// 8 splits -> 4 blocks/CU (vs 2) for latency hiding; K-splits combined via fp32 atomicAdd.
__global__ __launch_bounds__(256) void k2_attn(const int* __restrict__ adj,
                                               const short* __restrict__ hB,
                                               const float* __restrict__ t_ei,
                                               const float* __restrict__ t_E1i,
                                               const float* __restrict__ t_E2i,
                                               const float* __restrict__ t_nj,
                                               const float* __restrict__ t_E1j,
                                               const float* __restrict__ t_E2j,
                                               float* __restrict__ num,
                                               float* __restrict__ Lsum) {
    int w = threadIdx.x >> 6;                  // head
    int l = threadIdx.x & 63;
    int quad = l >> 4, lx = l & 15;
    int rb = blockIdx.x >> 3, ks = blockIdx.x & 7;
    int rowbase = rb * 64;
    int tb = w * NN;

    float eiv[4], E1i[4], E2i[4];
#pragma unroll
    for (int r = 0; r < 4; ++r) {
        int i = rowbase + r * 16 + lx;         // A row: lane&15
        eiv[r] = t_ei[tb + i];
        E1i[r] = t_E1i[tb + i];
        E2i[r] = t_E2i[tb + i];
    }

    f32x4 acc[4][4] = {};                      // [m-tile][o-tile]
    float Lacc[4] = {0.f, 0.f, 0.f, 0.f};
    int k0 = ks * 1024;

#pragma unroll 2
    for (int kt = 0; kt < 32; ++kt) {
        int kb = k0 + kt * 32 + quad * 8;      // this lane's 8-wide k slice
        f32x4 nj0  = *(const f32x4*)(t_nj  + tb + kb);
        f32x4 nj1  = *(const f32x4*)(t_nj  + tb + kb + 4);
        f32x4 e1j0 = *(const f32x4*)(t_E1j + tb + kb);
        f32x4 e1j1 = *(const f32x4*)(t_E1j + tb + kb + 4);
        f32x4 e2j0 = *(const f32x4*)(t_E2j + tb + kb);
        f32x4 e2j1 = *(const f32x4*)(t_E2j + tb + kb + 4);

        bf16x8 bfrag[4];
#pragma unroll
        for (int ot = 0; ot < 4; ++ot)         // B-frag: one 16B load
            bfrag[ot] = *(const bf16x8*)(hB + ((w * 1024 + (kb >> 3)) * 64 + ot * 16 + lx) * 8);

        bf16x8 afr[4];
#pragma unroll
        for (int r = 0; r < 4; ++r) {
            const int* ap = adj + (size_t)(rowbase + r * 16 + lx) * NN + kb;
            i32x4 a0 = *(const i32x4*)ap;
            i32x4 a1 = *(const i32x4*)(ap + 4);
            union { i32x4 i; bf16x8 b; } af;
            float lsum = 0.f;
#pragma unroll
            for (int jj = 0; jj < 4; ++jj) {   // two elements per iteration -> packed bf16
                int j0 = 2 * jj, j1 = 2 * jj + 1;
                int   av0 = (j0 < 4) ? a0[j0] : a1[j0 - 4];
                int   av1 = (j1 < 4) ? a0[j1] : a1[j1 - 4];
                float njA = (j0 < 4) ? nj0[j0] : nj1[j0 - 4];
                float njB = (j1 < 4) ? nj0[j1] : nj1[j1 - 4];
                float e1A = (j0 < 4) ? e1j0[j0] : e1j1[j0 - 4];
                float e1B = (j1 < 4) ? e1j0[j1] : e1j1[j1 - 4];
                float e2A = (j0 < 4) ? e2j0[j0] : e2j1[j0 - 4];
                float e2B = (j1 < 4) ? e2j0[j1] : e2j1[j1 - 4];
                bool  cA  = eiv[r] >= njA;     // s = ei+ej >= 0
                bool  cB  = eiv[r] >= njB;
                float p0  = (cA ? E1i[r] : E2i[r]) * (cA ? e1A : e2A);
                float p1  = (cB ? E1i[r] : E2i[r]) * (cB ? e1B : e2B);
                p0 = av0 ? p0 : 0.0f;          // adjacency mask
                p1 = av1 ? p1 : 0.0f;
                lsum += p0 + p1;               // denominator in fp32 (unrounded)
                unsigned u0 = __float_as_uint(p0) + 0x8000u;  // rne-ish bf16 round
                unsigned u1 = __float_as_uint(p1) + 0x8000u;
                af.i[jj] = (int)__builtin_amdgcn_perm(u1, u0, 0x07060302); // pack hi16|hi16
            }
            Lacc[r] += lsum;
            afr[r] = af.b;
        }
#pragma unroll
        for (int r = 0; r < 4; ++r)
#pragma unroll
            for (int ot = 0; ot < 4; ++ot)
                acc[r][ot] = __builtin_amdgcn_mfma_f32_16x16x32_bf16(afr[r], bfrag[ot], acc[r][ot], 0, 0, 0);
    }

    // softmax denominators: combine the 4 k-quads (lanes x, x^16, x^32)
#pragma unroll
    for (int r = 0; r < 4; ++r) {
        float L = Lacc[r];
        L += __shfl_xor(L, 16, 64);
        L += __shfl_xor(L, 32, 64);
        if (l < 16)
            atomicAdd(&Lsum[w * NN + rowbase + r * 16 + lx], L);
    }
    // numerator: atomic combine across the 8 K-splits
#pragma unroll
    for (int r = 0; r < 4; ++r)
#pragma unroll
        for (int ot = 0; ot < 4; ++ot)
#pragma unroll
            for (int reg = 0; reg < 4; ++reg) {
                int row = rowbase + r * 16 + quad * 4 + reg;    // C/D: row=quad*4+reg
                atomicAdd(&num[row * 256 + w * 64 + ot * 16 + lx], acc[r][ot][reg]);
            }
}

// ---------------- K3: divide by L in-place, BN partial stats -------------------------------
// grid 256 blocks x 32 rows; thread t = column c (h*64+o)
__global__ __launch_bounds__(256) void k3_combine(float* __restrict__ num,
                                                  const float* __restrict__ Lsum,
                                                  float* __restrict__ stats) {
    int c = threadIdx.x;
    int h = c >> 6;
    float s = 0.f, s2 = 0.f;
    for (int rr = 0; rr < 32; ++rr) {
        int row = blockIdx.x * 32 + rr;
        float L = Lsum[h * NN + row];
        float val = num[row * 256 + c] / L;
        num[row * 256 + c] = val;              // in-place: becomes preout
        s += val; s2 += val * val;
    }
    atomicAdd(&stats[c], s);
    atomicAdd(&stats[c + 256], s2);
}

// ---------------- K4: finalize BN scale/shift ----------------------------------------------
__global__ __launch_bounds__(256) void k4_bnfinal(const float* __restrict__ stats,
                                                  const float* __restrict__ gamma,
                                                  const float* __restrict__ beta,
                                                  float* __restrict__ bnp) {
    int c = threadIdx.x;
    float mean = stats[c] * (1.0f / NN);
    float var  = stats[c + 256] * (1.0f / NN) - mean * mean;
    float sc = gamma[c] * rsqrtf(var + BN_EPS);
    bnp[c] = sc;
    bnp[c + 256] = beta[c] - mean * sc;
}

// ---------------- K5: apply BN + ReLU -> fp32 out ------------------------------------------
__global__ __launch_bounds__(256) void k5_apply(const float* __restrict__ preout,
                                                const float* __restrict__ bnp,
                                                float* __restrict__ out) {
    int g = blockIdx.x * 256 + threadIdx.x;        // float4 index, 524288 total
    f32x4 v = *(const f32x4*)(preout + (size_t)g * 4);
    int cb = (g * 4) & 255;
    f32x4 r;
#pragma unroll
    for (int j = 0; j < 4; ++j)
        r[j] = fmaxf(v[j] * bnp[cb + j] + bnp[256 + cb + j], 0.0f);
    *(f32x4*)(out + (size_t)g * 4) = r;
}

extern "C" void kernel_launch(void* const* d_in, const int* in_sizes, int n_in,
                              void* d_out, int out_size, void* d_ws, size_t ws_size,
                              hipStream_t stream) {
    (void)in_sizes; (void)n_in; (void)out_size; (void)ws_size;
    const float* x     = (const float*)d_in[0];
    const int*   adj   = (const int*)d_in[1];
    const float* W     = (const float*)d_in[2];
    const float* a_i   = (const float*)d_in[3];
    const float* a_j   = (const float*)d_in[4];
    const float* gamma = (const float*)d_in[5];
    const float* beta  = (const float*)d_in[6];
    float* out = (float*)d_out;

    char* ws = (char*)d_ws;
    // workspace layout (~13.6 MB). num|Lsum|stats contiguous -> single memset.
    short* WB    = (short*)(ws + 0);              //   64 KB (bf16 W, B-frag layout)
    short* hB    = (short*)(ws + 65536);          //    4 MB (bf16 h, B-frag layout)
    float* t_ei  = (float*)(ws + 4259840);        // 6 x 128 KB tables
    float* t_E1i = t_ei + 32768;
    float* t_E2i = t_ei + 2 * 32768;
    float* t_nj  = t_ei + 3 * 32768;
    float* t_E1j = t_ei + 4 * 32768;
    float* t_E2j = t_ei + 5 * 32768;
    float* num   = (float*)(ws + 5046272);        //    8 MB (numerator -> preout in-place)
    float* Lsum  = (float*)(ws + 13434880);       //  128 KB
    float* stats = (float*)(ws + 13565952);       //    2 KB (atomic accum)
    float* bnp   = (float*)(ws + 13568000);       //    2 KB

    hipMemsetAsync(num, 0, 8388608 + 131072 + 2048, stream);  // num + Lsum + stats

    k0_repackW<<<dim3(128), dim3(256), 0, stream>>>(W, WB);
    k1_feat   <<<dim3(512), dim3(256), 0, stream>>>(x, WB, a_i, a_j, hB,
                                                    t_ei, t_E1i, t_E2i, t_nj, t_E1j, t_E2j);
    k2_attn   <<<dim3(1024), dim3(256), 0, stream>>>(adj, hB, t_ei, t_E1i, t_E2i,
                                                     t_nj, t_E1j, t_E2j, num, Lsum);
    k3_combine<<<dim3(256), dim3(256), 0, stream>>>(num, Lsum, stats);
    k4_bnfinal<<<dim3(1),   dim3(256), 0, stream>>>(stats, gamma, beta, bnp);
    k5_apply  <<<dim3(2048), dim3(256), 0, stream>>>(num, bnp, out);
}

// Round 7
// 492.288 us; speedup vs baseline: 1.2830x; 1.2830x over previous
//
#include <hip/hip_runtime.h>
#include <hip/hip_bf16.h>

// Problem constants (GATModule: N=8192, IN=128, OUT=64, H=4) — fp32 inputs/output.
#define NN   8192
#define IND  128
#define OUTD 64
#define NH   4
#define NEG_SLOPE 0.2f
#define BN_EPS 1e-5f

typedef __attribute__((ext_vector_type(8))) short bf16x8;   // MFMA A/B frag (8 bf16)
typedef __attribute__((ext_vector_type(4))) float f32x4;    // MFMA C/D frag
typedef __attribute__((ext_vector_type(4))) int   i32x4;

static __device__ __forceinline__ float bf2f(short s) {
    union { unsigned u; float f; } v; v.u = ((unsigned)(unsigned short)s) << 16; return v.f;
}
static __device__ __forceinline__ short f2bf(float f) {
    union { float f; unsigned u; } v; v.f = f;
    return (short)((v.u + 0x8000u) >> 16);
}

// ---------------- K0: repack W[h][k][o] fp32 -> WB bf16 [h][k/8][o][k%8] (B-frag) ----------
__global__ __launch_bounds__(256) void k0_repackW(const float* __restrict__ W,
                                                  short* __restrict__ WB) {
    int tid = blockIdx.x * 256 + threadIdx.x;      // 0..32767
    int o = tid & 63, i = (tid >> 6) & 127, h = tid >> 13;
    WB[((h * 16 + (i >> 3)) * 64 + o) * 8 + (i & 7)] = f2bf(W[(h * 128 + i) * 64 + o]);
}

// ---------------- K1: h = x@W per head (MFMA); store hB bf16 + exp tables ------------------
// grid 512 (16 rows each), block 256 (wave w = head w)
__global__ __launch_bounds__(256) void k1_feat(const float* __restrict__ x,
                                               const short* __restrict__ WB,
                                               const float* __restrict__ a_i,
                                               const float* __restrict__ a_j,
                                               short* __restrict__ hB,
                                               float* __restrict__ t_ei,  float* __restrict__ t_E1i,
                                               float* __restrict__ t_E2i, float* __restrict__ t_nj,
                                               float* __restrict__ t_E1j, float* __restrict__ t_E2j) {
    int w = threadIdx.x >> 6;        // head
    int l = threadIdx.x & 63;
    int quad = l >> 4, lx = l & 15;
    int rb = blockIdx.x;             // 16-row block

    f32x4 acc[4] = {};               // 4 o-tiles of 16
#pragma unroll
    for (int ks = 0; ks < 4; ++ks) { // K=128 in 4 steps of 32
        const float* xp = x + (rb * 16 + lx) * IND + ks * 32 + quad * 8;
        f32x4 xa = *(const f32x4*)xp;
        f32x4 xb = *(const f32x4*)(xp + 4);
        bf16x8 af;
#pragma unroll
        for (int j = 0; j < 4; ++j) { af[j] = f2bf(xa[j]); af[4 + j] = f2bf(xb[j]); }
#pragma unroll
        for (int ot = 0; ot < 4; ++ot) {
            bf16x8 bf = *(const bf16x8*)(WB + ((w * 16 + ks * 4 + quad) * 64 + ot * 16 + lx) * 8);
            acc[ot] = __builtin_amdgcn_mfma_f32_16x16x32_bf16(af, bf, acc[ot], 0, 0, 0);
        }
    }
    float aiv[4], ajv[4];
#pragma unroll
    for (int ot = 0; ot < 4; ++ot) {
        aiv[ot] = a_i[w * 64 + ot * 16 + lx];
        ajv[ot] = a_j[w * 64 + ot * 16 + lx];
    }
#pragma unroll
    for (int reg = 0; reg < 4; ++reg) {
        int row = rb * 16 + quad * 4 + reg;       // C-layout: row=quad*4+reg, col=lane&15
        float ei = 0.f, ej = 0.f;
#pragma unroll
        for (int ot = 0; ot < 4; ++ot) {
            float hv = acc[ot][reg];
            ei += hv * aiv[ot];
            ej += hv * ajv[ot];
        }
#pragma unroll
        for (int m = 1; m <= 8; m <<= 1) {        // reduce over the 16 lanes of this row
            ei += __shfl_xor(ei, m, 64);
            ej += __shfl_xor(ej, m, 64);
        }
        if (lx == reg) {
            t_ei [w * NN + row] = ei;
            t_E1i[w * NN + row] = expf(ei);
            t_E2i[w * NN + row] = expf(NEG_SLOPE * ei);
            t_nj [w * NN + row] = -ej;
            t_E1j[w * NN + row] = expf(ej);
            t_E2j[w * NN + row] = expf(NEG_SLOPE * ej);
        }
#pragma unroll
        for (int ot = 0; ot < 4; ++ot) {          // hB[h][n/8][o][n%8]
            int o = ot * 16 + lx;
            hB[((w * 1024 + (row >> 3)) * 64 + o) * 8 + (row & 7)] = f2bf(acc[ot][reg]);
        }
    }
}

// ---------------- K2: main attention kernel (software-pipelined) ---------------------------
// grid 512 = 128 rowblocks(64) x 4 K-splits(2048 cols); block 256 = 4 waves, wave w = head.
// Distance-1 register prefetch of adj + tables: kt+1's loads issue before kt's P-build,
// hiding ~900-cyc HBM latency behind ~500 cyc of VALU/MFMA at fixed (2 blocks/CU) occupancy.
__global__ __launch_bounds__(256) void k2_attn(const int* __restrict__ adj,
                                               const short* __restrict__ hB,
                                               const float* __restrict__ t_ei,
                                               const float* __restrict__ t_E1i,
                                               const float* __restrict__ t_E2i,
                                               const float* __restrict__ t_nj,
                                               const float* __restrict__ t_E1j,
                                               const float* __restrict__ t_E2j,
                                               float* __restrict__ num,
                                               float* __restrict__ Lsum) {
    int w = threadIdx.x >> 6;                  // head
    int l = threadIdx.x & 63;
    int quad = l >> 4, lx = l & 15;
    int rb = blockIdx.x >> 2, ks = blockIdx.x & 3;
    int rowbase = rb * 64;
    int tb = w * NN;

    float eiv[4], E1i[4], E2i[4];
#pragma unroll
    for (int r = 0; r < 4; ++r) {
        int i = rowbase + r * 16 + lx;         // A row: lane&15
        eiv[r] = t_ei[tb + i];
        E1i[r] = t_E1i[tb + i];
        E2i[r] = t_E2i[tb + i];
    }

    f32x4 acc[4][4] = {};                      // [m-tile][o-tile]
    float Lacc[4] = {0.f, 0.f, 0.f, 0.f};
    int k0 = ks * 2048;

    // -------- prefetch buffers (next iteration's adj + tables) --------
    i32x4 pa0[4], pa1[4];
    f32x4 pnj0, pnj1, pe10, pe11, pe20, pe21;
    {
        int kb = k0 + quad * 8;                // kt = 0
        pnj0 = *(const f32x4*)(t_nj  + tb + kb);
        pnj1 = *(const f32x4*)(t_nj  + tb + kb + 4);
        pe10 = *(const f32x4*)(t_E1j + tb + kb);
        pe11 = *(const f32x4*)(t_E1j + tb + kb + 4);
        pe20 = *(const f32x4*)(t_E2j + tb + kb);
        pe21 = *(const f32x4*)(t_E2j + tb + kb + 4);
#pragma unroll
        for (int r = 0; r < 4; ++r) {
            const int* ap = adj + (size_t)(rowbase + r * 16 + lx) * NN + kb;
            pa0[r] = *(const i32x4*)ap;
            pa1[r] = *(const i32x4*)(ap + 4);
        }
    }

#pragma unroll 1
    for (int kt = 0; kt < 64; ++kt) {
        // rotate: current <- prefetched
        f32x4 nj0 = pnj0, nj1 = pnj1;
        f32x4 e1j0 = pe10, e1j1 = pe11;
        f32x4 e2j0 = pe20, e2j1 = pe21;
        i32x4 a0c[4], a1c[4];
#pragma unroll
        for (int r = 0; r < 4; ++r) { a0c[r] = pa0[r]; a1c[r] = pa1[r]; }

        // issue NEXT iteration's loads first (wrap on last iter — harmless re-read)
        int ktn = (kt + 1) & 63;
        int kbn = k0 + ktn * 32 + quad * 8;
        pnj0 = *(const f32x4*)(t_nj  + tb + kbn);
        pnj1 = *(const f32x4*)(t_nj  + tb + kbn + 4);
        pe10 = *(const f32x4*)(t_E1j + tb + kbn);
        pe11 = *(const f32x4*)(t_E1j + tb + kbn + 4);
        pe20 = *(const f32x4*)(t_E2j + tb + kbn);
        pe21 = *(const f32x4*)(t_E2j + tb + kbn + 4);
#pragma unroll
        for (int r = 0; r < 4; ++r) {
            const int* ap = adj + (size_t)(rowbase + r * 16 + lx) * NN + kbn;
            pa0[r] = *(const i32x4*)ap;
            pa1[r] = *(const i32x4*)(ap + 4);
        }

        // B-frags for current kt
        int kb = k0 + kt * 32 + quad * 8;
        bf16x8 bfrag[4];
#pragma unroll
        for (int ot = 0; ot < 4; ++ot)         // B-frag: one 16B load
            bfrag[ot] = *(const bf16x8*)(hB + ((w * 1024 + (kb >> 3)) * 64 + ot * 16 + lx) * 8);

        // build P (A-frags) from current adj + tables
        bf16x8 afr[4];
#pragma unroll
        for (int r = 0; r < 4; ++r) {
            union { i32x4 i; bf16x8 b; } af;
            float lsum = 0.f;
#pragma unroll
            for (int jj = 0; jj < 4; ++jj) {   // two elements per iter -> packed bf16
                int j0 = 2 * jj, j1 = 2 * jj + 1;
                int   av0 = (j0 < 4) ? a0c[r][j0] : a1c[r][j0 - 4];
                int   av1 = (j1 < 4) ? a0c[r][j1] : a1c[r][j1 - 4];
                float njA = (j0 < 4) ? nj0[j0] : nj1[j0 - 4];
                float njB = (j1 < 4) ? nj0[j1] : nj1[j1 - 4];
                float e1A = (j0 < 4) ? e1j0[j0] : e1j1[j0 - 4];
                float e1B = (j1 < 4) ? e1j0[j1] : e1j1[j1 - 4];
                float e2A = (j0 < 4) ? e2j0[j0] : e2j1[j0 - 4];
                float e2B = (j1 < 4) ? e2j0[j1] : e2j1[j1 - 4];
                bool  cA  = eiv[r] >= njA;     // s = ei+ej >= 0
                bool  cB  = eiv[r] >= njB;
                float p0  = (cA ? E1i[r] : E2i[r]) * (cA ? e1A : e2A);
                float p1  = (cB ? E1i[r] : E2i[r]) * (cB ? e1B : e2B);
                p0 = av0 ? p0 : 0.0f;          // adjacency mask
                p1 = av1 ? p1 : 0.0f;
                lsum += p0 + p1;               // fp32 denominator
                unsigned u0 = __float_as_uint(p0) + 0x8000u;
                unsigned u1 = __float_as_uint(p1) + 0x8000u;
                af.i[jj] = (int)__builtin_amdgcn_perm(u1, u0, 0x07060302); // [p1.hi16|p0.hi16]
            }
            Lacc[r] += lsum;
            afr[r] = af.b;
        }
#pragma unroll
        for (int r = 0; r < 4; ++r)
#pragma unroll
            for (int ot = 0; ot < 4; ++ot)
                acc[r][ot] = __builtin_amdgcn_mfma_f32_16x16x32_bf16(afr[r], bfrag[ot], acc[r][ot], 0, 0, 0);
    }

    // softmax denominators: combine the 4 k-quads (lanes x, x^16, x^32)
#pragma unroll
    for (int r = 0; r < 4; ++r) {
        float L = Lacc[r];
        L += __shfl_xor(L, 16, 64);
        L += __shfl_xor(L, 32, 64);
        if (l < 16)
            atomicAdd(&Lsum[w * NN + rowbase + r * 16 + lx], L);
    }
    // numerator: atomic combine across the 4 K-splits
#pragma unroll
    for (int r = 0; r < 4; ++r)
#pragma unroll
        for (int ot = 0; ot < 4; ++ot)
#pragma unroll
            for (int reg = 0; reg < 4; ++reg) {
                int row = rowbase + r * 16 + quad * 4 + reg;    // C/D: row=quad*4+reg
                atomicAdd(&num[row * 256 + w * 64 + ot * 16 + lx], acc[r][ot][reg]);
            }
}

// ---------------- K3: divide by L in-place, BN partial stats -------------------------------
// grid 256 blocks x 32 rows; thread t = column c (h*64+o)
__global__ __launch_bounds__(256) void k3_combine(float* __restrict__ num,
                                                  const float* __restrict__ Lsum,
                                                  float* __restrict__ stats) {
    int c = threadIdx.x;
    int h = c >> 6;
    float s = 0.f, s2 = 0.f;
    for (int rr = 0; rr < 32; ++rr) {
        int row = blockIdx.x * 32 + rr;
        float L = Lsum[h * NN + row];
        float val = num[row * 256 + c] / L;
        num[row * 256 + c] = val;              // in-place: becomes preout
        s += val; s2 += val * val;
    }
    atomicAdd(&stats[c], s);
    atomicAdd(&stats[c + 256], s2);
}

// ---------------- K4: finalize BN scale/shift ----------------------------------------------
__global__ __launch_bounds__(256) void k4_bnfinal(const float* __restrict__ stats,
                                                  const float* __restrict__ gamma,
                                                  const float* __restrict__ beta,
                                                  float* __restrict__ bnp) {
    int c = threadIdx.x;
    float mean = stats[c] * (1.0f / NN);
    float var  = stats[c + 256] * (1.0f / NN) - mean * mean;
    float sc = gamma[c] * rsqrtf(var + BN_EPS);
    bnp[c] = sc;
    bnp[c + 256] = beta[c] - mean * sc;
}

// ---------------- K5: apply BN + ReLU -> fp32 out ------------------------------------------
__global__ __launch_bounds__(256) void k5_apply(const float* __restrict__ preout,
                                                const float* __restrict__ bnp,
                                                float* __restrict__ out) {
    int g = blockIdx.x * 256 + threadIdx.x;        // float4 index, 524288 total
    f32x4 v = *(const f32x4*)(preout + (size_t)g * 4);
    int cb = (g * 4) & 255;
    f32x4 r;
#pragma unroll
    for (int j = 0; j < 4; ++j)
        r[j] = fmaxf(v[j] * bnp[cb + j] + bnp[256 + cb + j], 0.0f);
    *(f32x4*)(out + (size_t)g * 4) = r;
}

extern "C" void kernel_launch(void* const* d_in, const int* in_sizes, int n_in,
                              void* d_out, int out_size, void* d_ws, size_t ws_size,
                              hipStream_t stream) {
    (void)in_sizes; (void)n_in; (void)out_size; (void)ws_size;
    const float* x     = (const float*)d_in[0];
    const int*   adj   = (const int*)d_in[1];
    const float* W     = (const float*)d_in[2];
    const float* a_i   = (const float*)d_in[3];
    const float* a_j   = (const float*)d_in[4];
    const float* gamma = (const float*)d_in[5];
    const float* beta  = (const float*)d_in[6];
    float* out = (float*)d_out;

    char* ws = (char*)d_ws;
    // workspace layout (~13.6 MB). num|Lsum|stats contiguous -> single memset.
    short* WB    = (short*)(ws + 0);              //   64 KB (bf16 W, B-frag layout)
    short* hB    = (short*)(ws + 65536);          //    4 MB (bf16 h, B-frag layout)
    float* t_ei  = (float*)(ws + 4259840);        // 6 x 128 KB tables
    float* t_E1i = t_ei + 32768;
    float* t_E2i = t_ei + 2 * 32768;
    float* t_nj  = t_ei + 3 * 32768;
    float* t_E1j = t_ei + 4 * 32768;
    float* t_E2j = t_ei + 5 * 32768;
    float* num   = (float*)(ws + 5046272);        //    8 MB (numerator -> preout in-place)
    float* Lsum  = (float*)(ws + 13434880);       //  128 KB
    float* stats = (float*)(ws + 13565952);       //    2 KB (atomic accum)
    float* bnp   = (float*)(ws + 13568000);       //    2 KB

    hipMemsetAsync(num, 0, 8388608 + 131072 + 2048, stream);  // num + Lsum + stats

    k0_repackW<<<dim3(128), dim3(256), 0, stream>>>(W, WB);
    k1_feat   <<<dim3(512), dim3(256), 0, stream>>>(x, WB, a_i, a_j, hB,
                                                    t_ei, t_E1i, t_E2i, t_nj, t_E1j, t_E2j);
    k2_attn   <<<dim3(512), dim3(256), 0, stream>>>(adj, hB, t_ei, t_E1i, t_E2i,
                                                    t_nj, t_E1j, t_E2j, num, Lsum);
    k3_combine<<<dim3(256), dim3(256), 0, stream>>>(num, Lsum, stats);
    k4_bnfinal<<<dim3(1),   dim3(256), 0, stream>>>(stats, gamma, beta, bnp);
    k5_apply  <<<dim3(2048), dim3(256), 0, stream>>>(num, bnp, out);
}